// Round 2
// baseline (418.488 us; speedup 1.0000x reference)
//
#include <hip/hip_runtime.h>
#include <stdint.h>

// Block-sparse linear: out[8192,4096] = x @ W^T + bias, W BSR 64x64 blocks.
// R5: de-risked pipeline re-land. R3 (148us GEMM, 928 TF) was limited by the
// per-step stage->vmcnt(0)-drain->compute serialization (MfmaUtil 41%, HBM
// 13%, conflicts 0). R4 (3-buf, raw s_barrier + counted vmcnt(6), 144 KiB
// LDS) never ran: container failed; 144 KiB static LDS and hand-rolled
// barrier placement were the risk factors. R5 applies the guide's proven
// minimum 2-phase recipe instead: double-buffer (96 KiB), issue stage(t+1)
// BEFORE compute(t), ONE __syncthreads() per step (vmcnt drain now pays only
// the latency left over after the compute phase). No inline-asm waits.
// Merge table precomputed into lane registers so staging runs a step ahead.

#define BATCH   8192
#define IN_F    4096
#define OUT_F   4096
#define BS      64
#define NROW    64
#define NNZB    2048
#define BM      256                        // batch rows per workgroup
#define LDS_A_BYTES 32768                  // BM x BS x 2
#define LDS_B_BYTES 16384                  // two W blocks
#define BUF_BYTES   (LDS_A_BYTES + LDS_B_BYTES)   // 49152
#define NBUF    2                          // 98304 B LDS (proven-compilable)

typedef float f32x4 __attribute__((ext_vector_type(4)));
typedef short s16x8 __attribute__((ext_vector_type(8)));   // 8 x bf16

__device__ __forceinline__ void async_copy16(const void* g, void* l) {
  // global -> LDS direct DMA, 16 B/lane. LDS dest = wave base + lane*16.
  __builtin_amdgcn_global_load_lds(
      (__attribute__((address_space(1))) void*)g,
      (__attribute__((address_space(3))) void*)l, 16, 0, 0);
}

__device__ __forceinline__ unsigned short f32_to_bf16(float f) {
  union { float f; uint32_t u; } v; v.f = f;
  return (unsigned short)((v.u + 0x7FFFu + ((v.u >> 16) & 1u)) >> 16);
}

// Single fused cvt for x and values (one launch instead of two).
__global__ void cvt_kernel(const float4* __restrict__ xin,
                           const float4* __restrict__ win,
                           ushort4* __restrict__ xout,
                           ushort4* __restrict__ wout, int nx4, int ntot4) {
  int i = blockIdx.x * blockDim.x + threadIdx.x;
  if (i >= ntot4) return;
  const float4* src; ushort4* dst; int j;
  if (i < nx4) { src = xin; dst = xout; j = i; }
  else         { src = win; dst = wout; j = i - nx4; }
  float4 v = src[j];
  ushort4 o;
  o.x = f32_to_bf16(v.x); o.y = f32_to_bf16(v.y);
  o.z = f32_to_bf16(v.z); o.w = f32_to_bf16(v.w);
  dst[j] = o;
}

// GEMM: grid (NROW/2=32 pairs, BATCH/BM=32), block 512 = 8 waves.
// Pair p -> rows rA=(p>>1)*4+(p&1), rB=rA+2 (same parity -> same cols in
// this dataset; merge table handles arbitrary overlap). Wave w: wm=w&3
// (64-row m-quarter), wn=w>>2 (which block-row). LDS swizzle (verified 0
// conflicts in R2/R3): chunk slot s of row r holds global 16B-chunk
// (s ^ (r&7)).
__global__ __launch_bounds__(512) void bsr_gemm_pair_kernel(
    const unsigned short* __restrict__ xb,   // bf16 [BATCH][IN_F]
    const unsigned short* __restrict__ wb,   // bf16 [NNZB][64][64] ([n][k])
    const float* __restrict__ bias,
    const int* __restrict__ crow,
    const int* __restrict__ cols,
    float* __restrict__ out) {
  __shared__ alignas(16) char smem[NBUF * BUF_BYTES];

  const int tid = threadIdx.x;
  const int w   = tid >> 6;        // wave 0..7
  const int l   = tid & 63;        // lane
  const int wm  = w & 3;           // m-quarter
  const int wn  = w >> 2;          // block-row within pair (0=A,1=B)
  const int p   = blockIdx.x;
  const int rA  = ((p >> 1) << 2) + (p & 1);
  const int rB  = rA + 2;
  const int m0  = blockIdx.y * BM;

  const int startA = crow[rA], endA = crow[rA + 1];
  const int startB = crow[rB], endB = crow[rB + 1];

  const int lr = l & 15;           // MFMA m/n index within 16
  const int q  = l >> 4;           // quad 0..3

  // Preload both sorted col lists into lane registers (<=64 entries each).
  int cvA = (startA + l < endA) ? cols[startA + l] : 0;
  int cvB = (startB + l < endB) ? cols[startB + l] : 0;

  // ---- Precompute merged step table into lane-indexed registers. ----
  // Lane t holds step t: col (myc) and packed {sA, sB, hasA, hasB} (mypk).
  // Union of two col-sets over NCOL=64 -> nt <= 64 steps, fits the wave.
  // sA/sB are CLAMPED valid block indices so staging is always 6 loads/step
  // (branchless, uniform schedule).
  int myc = 0, mypk = 0;
  int nt = 0;
  {
    int ia = startA, ib = startB;
    const int clA = (endA > startA) ? endA - 1 : 0;
    const int clB = (endB > startB) ? endB - 1 : 0;
    while ((ia < endA) || (ib < endB)) {
      const int ca = (ia < endA) ? __shfl(cvA, ia - startA) : 0x7fffffff;
      const int cb = (ib < endB) ? __shfl(cvB, ib - startB) : 0x7fffffff;
      const int c  = min(ca, cb);
      const int hA = (ca == c);
      const int hB = (cb == c);
      const int sA = hA ? ia : clA;
      const int sB = hB ? ib : clB;
      if (nt == l) { myc = c; mypk = sA | (sB << 12) | (hA << 24) | (hB << 25); }
      ia += hA; ib += hB; ++nt;
    }
  }

  f32x4 acc[4][4];
#pragma unroll
  for (int mi = 0; mi < 4; ++mi)
#pragma unroll
    for (int ni = 0; ni < 4; ++ni) {
      f32x4 z = {0.f, 0.f, 0.f, 0.f};
      acc[mi][ni] = z;
    }

  // Staging lane roles (512 threads): row-within-issue = tid>>3 (0..63),
  // chunk slot = tid&7, swizzled global chunk = slot ^ (row&7).
  const int srow = tid >> 3;
  const int sswz = ((tid & 7) ^ (srow & 7)) << 3;              // elements
  const unsigned short* agbase =
      xb + (size_t)(m0 + srow) * IN_F + sswz;                  // + c*64
  const int bgoff = (srow << 6) + sswz;                        // elements

  // Issue the 6 global_load_lds for step t into buffer buf (no waits here).
  auto stage = [&](int t, int buf) {
    const int c  = __shfl(myc, t);
    const int pk = __shfl(mypk, t);
    const int sA = pk & 0xfff;
    const int sB = (pk >> 12) & 0xfff;
    char* const al = smem + buf * BUF_BYTES + tid * 16;
    char* const bl = smem + buf * BUF_BYTES + LDS_A_BYTES + tid * 16;
    const unsigned short* ag = agbase + (size_t)c * BS;
#pragma unroll
    for (int it = 0; it < 4; ++it)                 // A: 256 rows x 128 B
      async_copy16(ag + (size_t)(it * 64) * IN_F, al + it * 8192);
    async_copy16(wb + ((size_t)sA << 12) + bgoff, bl);          // B for rA
    async_copy16(wb + ((size_t)sB << 12) + bgoff, bl + 8192);   // B for rB
  };

  // ---- 2-phase pipelined K-loop (guide §5.5 T3 minimum recipe). ----
  // Per step: issue stage(t+1) FIRST (latency hides under compute(t)),
  // compute from buf[cur], then ONE __syncthreads() (vmcnt(0)+lgkmcnt(0)+
  // barrier): (a) this wave's stage(t+1) loads drained -> next compute safe;
  // (b) all waves done reading buf[cur] -> next iter may stage into it.
  if (nt > 0) stage(0, 0);
  __syncthreads();
  int cur = 0;
  for (int t = 0; t < nt; ++t) {
    if (t + 1 < nt) stage(t + 1, cur ^ 1);

    const int pk = __shfl(mypk, t);
    const char* const cbase = smem + cur * BUF_BYTES;
    if ((pk >> (24 + wn)) & 1) {                   // this wave's row has col c
      __builtin_amdgcn_s_setprio(1);
#pragma unroll
      for (int ks = 0; ks < 2; ++ks) {
        const int chunk = (((ks << 2) + q) ^ (l & 7)) << 4;    // bytes
        s16x8 af[4], bf[4];
#pragma unroll
        for (int mi = 0; mi < 4; ++mi)   // A[m][k], swizzled chunk
          af[mi] = *(const s16x8*)(cbase +
                     ((wm << 6) + (mi << 4) + lr) * 128 + chunk);
#pragma unroll
        for (int ni = 0; ni < 4; ++ni)   // B^T[n][k], region wn
          bf[ni] = *(const s16x8*)(cbase + LDS_A_BYTES + (wn << 13) +
                     ((ni << 4) + lr) * 128 + chunk);
#pragma unroll
        for (int mi = 0; mi < 4; ++mi)
#pragma unroll
          for (int ni = 0; ni < 4; ++ni)
            acc[mi][ni] = __builtin_amdgcn_mfma_f32_16x16x32_bf16(
                af[mi], bf[ni], acc[mi][ni], 0, 0, 0);
      }
      __builtin_amdgcn_s_setprio(0);
    }
    __syncthreads();
    cur ^= 1;
  }

  // Epilogue: C/D layout col=lr, row=q*4+reg. Add bias, store fp32.
  const int rW = wn ? rB : rA;
  const int colg = (rW << 6) + lr;
#pragma unroll
  for (int ni = 0; ni < 4; ++ni) {
    const float bv = bias[colg + (ni << 4)];
#pragma unroll
    for (int mi = 0; mi < 4; ++mi) {
      float* op = out +
          (size_t)(m0 + (wm << 6) + (mi << 4) + (q << 2)) * OUT_F +
          colg + (ni << 4);
#pragma unroll
      for (int e = 0; e < 4; ++e)
        op[(size_t)e * OUT_F] = acc[mi][ni][e] + bv;
    }
  }
}

// Safety net if ws_size < 84 MB: naive fp32, one thread per output element.
__global__ void fallback_kernel(const float* __restrict__ x,
                                const float* __restrict__ vals,
                                const float* __restrict__ bias,
                                const int* __restrict__ crow,
                                const int* __restrict__ cols,
                                float* __restrict__ out) {
  int idx = blockIdx.x * 256 + threadIdx.x;
  int m = idx >> 12;
  int n = idx & 4095;
  int r = n >> 6, nl = n & 63;
  float s = 0.f;
  int e = crow[r + 1];
  for (int i = crow[r]; i < e; ++i) {
    const float* xp = x + (size_t)m * IN_F + cols[i] * 64;
    const float* wp = vals + ((size_t)i << 12) + nl * 64;
    for (int k = 0; k < 64; ++k) s += xp[k] * wp[k];
  }
  out[idx] = s + bias[n];
}

extern "C" void kernel_launch(void* const* d_in, const int* in_sizes, int n_in,
                              void* d_out, int out_size, void* d_ws,
                              size_t ws_size, hipStream_t stream) {
  const float* x    = (const float*)d_in[0];
  const float* vals = (const float*)d_in[1];
  const float* bias = (const float*)d_in[2];
  const int*   crow = (const int*)d_in[3];
  const int*   cols = (const int*)d_in[4];
  float* out = (float*)d_out;

  const size_t x_elems = (size_t)BATCH * IN_F;       // 33.5M
  const size_t w_elems = (size_t)NNZB * BS * BS;     // 8.4M
  const size_t need = (x_elems + w_elems) * 2;       // bf16 bytes, ~84 MB

  if (ws_size >= need) {
    unsigned short* xb = (unsigned short*)d_ws;
    unsigned short* wbp = xb + x_elems;
    const int nx4 = (int)(x_elems / 4);
    const int ntot4 = (int)((x_elems + w_elems) / 4);
    cvt_kernel<<<(ntot4 + 255) / 256, 256, 0, stream>>>(
        (const float4*)x, (const float4*)vals,
        (ushort4*)xb, (ushort4*)wbp, nx4, ntot4);
    dim3 grid(NROW / 2, BATCH / BM);  // pair-fast: same x-slab hot in L2
    bsr_gemm_pair_kernel<<<grid, 512, 0, stream>>>(xb, wbp, bias, crow, cols,
                                                   out);
  } else {
    fallback_kernel<<<(BATCH * OUT_F) / 256, 256, 0, stream>>>(
        x, vals, bias, crow, cols, out);
  }
}

// Round 3
// 391.843 us; speedup vs baseline: 1.0680x; 1.0680x over previous
//
#include <hip/hip_runtime.h>
#include <stdint.h>

// Block-sparse linear: out[8192,4096] = x @ W^T + bias, W BSR 64x64 blocks.
// R6: double-buffer WITHIN the 48KB footprint. R5 proved the 2-phase pipeline
// works but 96KB LDS killed 2-WG/CU residency (occ 39->21%, GEMM 148->208us):
// R3's perf was partly cross-WG TLP. Fix: halve stage depth to BK=32 ->
// 2 x 24KB buffers = 49152 B total (same LDS_Block_Size as R3 -> same
// residency), stage(h+1) issued BEFORE compute(h), ONE __syncthreads per
// half-step. Model: LDS pipe floor ~112us (reads 128KB/col/WG at 85B/cy);
// R3's 148us = floor + exposed drain; this should land ~115-125us.
// Swizzle re-derived for 64B rows: LDS slot s of row r holds global 16B
// chunk (s ^ (r&3)) -> uniform bank-group load on ds_read_b128.

#define BATCH   8192
#define IN_F    4096
#define OUT_F   4096
#define BS      64
#define BK      32                         // k-depth per stage (half col-step)
#define NROW    64
#define NNZB    2048
#define BM      256                        // batch rows per workgroup
#define LDS_A_BYTES (BM * BK * 2)          // 16384
#define LDS_B_BYTES (2 * BS * BK * 2)      // 8192 (two W half-blocks)
#define BUF_BYTES   (LDS_A_BYTES + LDS_B_BYTES)   // 24576
#define NBUF    2                          // 49152 B total == R3 footprint

typedef float f32x4 __attribute__((ext_vector_type(4)));
typedef short s16x8 __attribute__((ext_vector_type(8)));   // 8 x bf16

__device__ __forceinline__ void async_copy16(const void* g, void* l) {
  // global -> LDS direct DMA, 16 B/lane. LDS dest = wave base + lane*16.
  __builtin_amdgcn_global_load_lds(
      (__attribute__((address_space(1))) void*)g,
      (__attribute__((address_space(3))) void*)l, 16, 0, 0);
}

__device__ __forceinline__ unsigned short f32_to_bf16(float f) {
  union { float f; uint32_t u; } v; v.f = f;
  return (unsigned short)((v.u + 0x7FFFu + ((v.u >> 16) & 1u)) >> 16);
}

// Single fused cvt for x and values (one launch instead of two).
__global__ void cvt_kernel(const float4* __restrict__ xin,
                           const float4* __restrict__ win,
                           ushort4* __restrict__ xout,
                           ushort4* __restrict__ wout, int nx4, int ntot4) {
  int i = blockIdx.x * blockDim.x + threadIdx.x;
  if (i >= ntot4) return;
  const float4* src; ushort4* dst; int j;
  if (i < nx4) { src = xin; dst = xout; j = i; }
  else         { src = win; dst = wout; j = i - nx4; }
  float4 v = src[j];
  ushort4 o;
  o.x = f32_to_bf16(v.x); o.y = f32_to_bf16(v.y);
  o.z = f32_to_bf16(v.z); o.w = f32_to_bf16(v.w);
  dst[j] = o;
}

// GEMM: grid (NROW/2=32 pairs, BATCH/BM=32), block 512 = 8 waves.
// Pair p -> rows rA=(p>>1)*4+(p&1), rB=rA+2 (same parity -> same cols in
// this dataset; merge table handles arbitrary overlap). Wave w: wm=w&3
// (64-row m-quarter), wn=w>>2 (which block-row of the pair).
__global__ __launch_bounds__(512) void bsr_gemm_pair_kernel(
    const unsigned short* __restrict__ xb,   // bf16 [BATCH][IN_F]
    const unsigned short* __restrict__ wb,   // bf16 [NNZB][64][64] ([n][k])
    const float* __restrict__ bias,
    const int* __restrict__ crow,
    const int* __restrict__ cols,
    float* __restrict__ out) {
  __shared__ alignas(16) char smem[NBUF * BUF_BYTES];

  const int tid = threadIdx.x;
  const int w   = tid >> 6;        // wave 0..7
  const int l   = tid & 63;        // lane
  const int wm  = w & 3;           // m-quarter
  const int wn  = w >> 2;          // block-row within pair (0=A,1=B)
  const int p   = blockIdx.x;
  const int rA  = ((p >> 1) << 2) + (p & 1);
  const int rB  = rA + 2;
  const int m0  = blockIdx.y * BM;

  const int startA = crow[rA], endA = crow[rA + 1];
  const int startB = crow[rB], endB = crow[rB + 1];

  const int lr = l & 15;           // MFMA m/n index within 16
  const int q  = l >> 4;           // quad 0..3 (k-chunk owner)

  // Preload both sorted col lists into lane registers (<=64 entries each).
  int cvA = (startA + l < endA) ? cols[startA + l] : 0;
  int cvB = (startB + l < endB) ? cols[startB + l] : 0;

  // ---- Precompute merged step table into lane-indexed registers. ----
  // Lane t holds step t: col (myc) and packed {sA, sB, hasA, hasB} (mypk).
  // sA/sB CLAMPED valid indices -> staging is branchless/uniform.
  int myc = 0, mypk = 0;
  int nt = 0;
  {
    int ia = startA, ib = startB;
    const int clA = (endA > startA) ? endA - 1 : 0;
    const int clB = (endB > startB) ? endB - 1 : 0;
    while ((ia < endA) || (ib < endB)) {
      const int ca = (ia < endA) ? __shfl(cvA, ia - startA) : 0x7fffffff;
      const int cb = (ib < endB) ? __shfl(cvB, ib - startB) : 0x7fffffff;
      const int c  = min(ca, cb);
      const int hA = (ca == c);
      const int hB = (cb == c);
      const int sA = hA ? ia : clA;
      const int sB = hB ? ib : clB;
      if (nt == l) { myc = c; mypk = sA | (sB << 12) | (hA << 24) | (hB << 25); }
      ia += hA; ib += hB; ++nt;
    }
  }

  f32x4 acc[4][4];
#pragma unroll
  for (int mi = 0; mi < 4; ++mi)
#pragma unroll
    for (int ni = 0; ni < 4; ++ni) {
      f32x4 z = {0.f, 0.f, 0.f, 0.f};
      acc[mi][ni] = z;
    }

  // Staging lane roles (512 threads, 64B rows now):
  // A issue: row = it*128 + (tid>>2), slot = tid&3, global chunk =
  //   slot ^ (row&3) = (tid&3) ^ ((tid>>2)&3). 2 issues x 8KB = 16KB.
  // B issue: block = tid>>8 (wave-uniform), n = (tid&255)>>2, same swizzle.
  const int swz8 = (((tid & 3) ^ ((tid >> 2) & 3)) << 3);      // elements
  const unsigned short* agbase =
      xb + (size_t)(m0 + (tid >> 2)) * IN_F + swz8;            // + c*64 + k0
  const int bgoff = (((tid & 255) >> 2) << 6) + swz8;          // elements
  const int bblk = tid >> 8;                                   // 0 or 1

  // Issue the 3 global_load_lds for half-step h into buffer buf.
  auto stage = [&](int h, int buf) {
    const int t  = h >> 1;
    const int k0 = (h & 1) << 5;                               // 0 or 32
    const int c  = __shfl(myc, t);
    const int pk = __shfl(mypk, t);
    const int sA = pk & 0xfff;
    const int sB = (pk >> 12) & 0xfff;
    char* const al = smem + buf * BUF_BYTES + tid * 16;
    char* const bl = smem + buf * BUF_BYTES + LDS_A_BYTES + tid * 16;
    const unsigned short* ag = agbase + (size_t)c * BS + k0;
    async_copy16(ag, al);                                      // rows 0..127
    async_copy16(ag + (size_t)128 * IN_F, al + 8192);          // rows 128..255
    const int sblk = bblk ? sB : sA;
    async_copy16(wb + ((size_t)sblk << 12) + bgoff + k0, bl);  // both W halves
  };

  // ---- 2-phase pipelined loop over half-steps (BK=32). ----
  // stage(h+1) issued first (latency hides under compute(h) + other WG),
  // compute reads buf[cur], ONE __syncthreads per half-step drains
  // vmcnt (stage h+1 complete) and fences buf[cur] for reuse.
  const int nh = nt << 1;
  if (nh > 0) stage(0, 0);
  __syncthreads();
  int cur = 0;
  for (int h = 0; h < nh; ++h) {
    if (h + 1 < nh) stage(h + 1, cur ^ 1);

    const int pk = __shfl(mypk, h >> 1);
    const char* const cbase = smem + cur * BUF_BYTES;
    if ((pk >> (24 + wn)) & 1) {                   // this wave's row has col c
      __builtin_amdgcn_s_setprio(1);
      const int chunk = ((q ^ (lr & 3)) << 4);     // bytes within 64B row
      s16x8 af[4], bf[4];
#pragma unroll
      for (int mi = 0; mi < 4; ++mi)   // A[m][k], swizzled chunk
        af[mi] = *(const s16x8*)(cbase +
                   ((wm << 6) + (mi << 4) + lr) * 64 + chunk);
#pragma unroll
      for (int ni = 0; ni < 4; ++ni)   // B^T[n][k], block wn
        bf[ni] = *(const s16x8*)(cbase + LDS_A_BYTES + (wn << 12) +
                   ((ni << 4) + lr) * 64 + chunk);
#pragma unroll
      for (int mi = 0; mi < 4; ++mi)
#pragma unroll
        for (int ni = 0; ni < 4; ++ni)
          acc[mi][ni] = __builtin_amdgcn_mfma_f32_16x16x32_bf16(
              af[mi], bf[ni], acc[mi][ni], 0, 0, 0);
      __builtin_amdgcn_s_setprio(0);
    }
    __syncthreads();
    cur ^= 1;
  }

  // Epilogue: C/D layout col=lr, row=q*4+reg. Add bias, store fp32.
  const int rW = wn ? rB : rA;
  const int colg = (rW << 6) + lr;
#pragma unroll
  for (int ni = 0; ni < 4; ++ni) {
    const float bv = bias[colg + (ni << 4)];
#pragma unroll
    for (int mi = 0; mi < 4; ++mi) {
      float* op = out +
          (size_t)(m0 + (wm << 6) + (mi << 4) + (q << 2)) * OUT_F +
          colg + (ni << 4);
#pragma unroll
      for (int e = 0; e < 4; ++e)
        op[(size_t)e * OUT_F] = acc[mi][ni][e] + bv;
    }
  }
}

// Safety net if ws_size < 84 MB: naive fp32, one thread per output element.
__global__ void fallback_kernel(const float* __restrict__ x,
                                const float* __restrict__ vals,
                                const float* __restrict__ bias,
                                const int* __restrict__ crow,
                                const int* __restrict__ cols,
                                float* __restrict__ out) {
  int idx = blockIdx.x * 256 + threadIdx.x;
  int m = idx >> 12;
  int n = idx & 4095;
  int r = n >> 6, nl = n & 63;
  float s = 0.f;
  int e = crow[r + 1];
  for (int i = crow[r]; i < e; ++i) {
    const float* xp = x + (size_t)m * IN_F + cols[i] * 64;
    const float* wp = vals + ((size_t)i << 12) + nl * 64;
    for (int k = 0; k < 64; ++k) s += xp[k] * wp[k];
  }
  out[idx] = s + bias[n];
}

extern "C" void kernel_launch(void* const* d_in, const int* in_sizes, int n_in,
                              void* d_out, int out_size, void* d_ws,
                              size_t ws_size, hipStream_t stream) {
  const float* x    = (const float*)d_in[0];
  const float* vals = (const float*)d_in[1];
  const float* bias = (const float*)d_in[2];
  const int*   crow = (const int*)d_in[3];
  const int*   cols = (const int*)d_in[4];
  float* out = (float*)d_out;

  const size_t x_elems = (size_t)BATCH * IN_F;       // 33.5M
  const size_t w_elems = (size_t)NNZB * BS * BS;     // 8.4M
  const size_t need = (x_elems + w_elems) * 2;       // bf16 bytes, ~84 MB

  if (ws_size >= need) {
    unsigned short* xb = (unsigned short*)d_ws;
    unsigned short* wbp = xb + x_elems;
    const int nx4 = (int)(x_elems / 4);
    const int ntot4 = (int)((x_elems + w_elems) / 4);
    cvt_kernel<<<(ntot4 + 255) / 256, 256, 0, stream>>>(
        (const float4*)x, (const float4*)vals,
        (ushort4*)xb, (ushort4*)wbp, nx4, ntot4);
    dim3 grid(NROW / 2, BATCH / BM);  // pair-fast: same x-slab hot in L2
    bsr_gemm_pair_kernel<<<grid, 512, 0, stream>>>(xb, wbp, bias, crow, cols,
                                                   out);
  } else {
    fallback_kernel<<<(BATCH * OUT_F) / 256, 256, 0, stream>>>(
        x, vals, bias, crow, cols, out);
  }
}

// Round 4
// 388.547 us; speedup vs baseline: 1.0771x; 1.0085x over previous
//
#include <hip/hip_runtime.h>
#include <stdint.h>

// Block-sparse linear: out[8192,4096] = x @ W^T + bias, W BSR 64x64 blocks.
// R7: fix the BK=32 LDS swizzle. R6 (2x24KB dbuf pipeline, occ back to 40%)
// regressed to 171us because the 64B-row swizzle g(r)=r&3 made ds_read_b128
// bank-start depend only on lr&3 -> 4-way conflict (1.678e7 cycles ~= 27us,
// exactly the R3->R6 delta). A 64B row spans HALF the banks: bank-start =
// (row&1)*16 + slot*4, so the XOR must use row bits ABOVE the parity bit:
// g(r) = (r>>1)&3. Then (lr&1, (lr>>1)&3) covers all 8 bank-quad starts
// exactly 2x -> 2-way aliasing = free (m136). Staging fetches global chunk
// (tid&3)^((tid>>3)&3); reads use slot q^((lr>>1)&3). Everything else (2x
// 24KB dbuf, stage-before-compute, one __syncthreads/half-step, setprio)
// unchanged from R6.

#define BATCH   8192
#define IN_F    4096
#define OUT_F   4096
#define BS      64
#define BK      32                         // k-depth per stage (half col-step)
#define NROW    64
#define NNZB    2048
#define BM      256                        // batch rows per workgroup
#define LDS_A_BYTES (BM * BK * 2)          // 16384
#define LDS_B_BYTES (2 * BS * BK * 2)      // 8192 (two W half-blocks)
#define BUF_BYTES   (LDS_A_BYTES + LDS_B_BYTES)   // 24576
#define NBUF    2                          // 49152 B total == R3 footprint

typedef float f32x4 __attribute__((ext_vector_type(4)));
typedef short s16x8 __attribute__((ext_vector_type(8)));   // 8 x bf16

__device__ __forceinline__ void async_copy16(const void* g, void* l) {
  // global -> LDS direct DMA, 16 B/lane. LDS dest = wave base + lane*16.
  __builtin_amdgcn_global_load_lds(
      (__attribute__((address_space(1))) void*)g,
      (__attribute__((address_space(3))) void*)l, 16, 0, 0);
}

__device__ __forceinline__ unsigned short f32_to_bf16(float f) {
  union { float f; uint32_t u; } v; v.f = f;
  return (unsigned short)((v.u + 0x7FFFu + ((v.u >> 16) & 1u)) >> 16);
}

// Single fused cvt for x and values (one launch instead of two).
__global__ void cvt_kernel(const float4* __restrict__ xin,
                           const float4* __restrict__ win,
                           ushort4* __restrict__ xout,
                           ushort4* __restrict__ wout, int nx4, int ntot4) {
  int i = blockIdx.x * blockDim.x + threadIdx.x;
  if (i >= ntot4) return;
  const float4* src; ushort4* dst; int j;
  if (i < nx4) { src = xin; dst = xout; j = i; }
  else         { src = win; dst = wout; j = i - nx4; }
  float4 v = src[j];
  ushort4 o;
  o.x = f32_to_bf16(v.x); o.y = f32_to_bf16(v.y);
  o.z = f32_to_bf16(v.z); o.w = f32_to_bf16(v.w);
  dst[j] = o;
}

// GEMM: grid (NROW/2=32 pairs, BATCH/BM=32), block 512 = 8 waves.
// Pair p -> rows rA=(p>>1)*4+(p&1), rB=rA+2 (same parity -> same cols in
// this dataset; merge table handles arbitrary overlap). Wave w: wm=w&3
// (64-row m-quarter), wn=w>>2 (which block-row of the pair).
__global__ __launch_bounds__(512) void bsr_gemm_pair_kernel(
    const unsigned short* __restrict__ xb,   // bf16 [BATCH][IN_F]
    const unsigned short* __restrict__ wb,   // bf16 [NNZB][64][64] ([n][k])
    const float* __restrict__ bias,
    const int* __restrict__ crow,
    const int* __restrict__ cols,
    float* __restrict__ out) {
  __shared__ alignas(16) char smem[NBUF * BUF_BYTES];

  const int tid = threadIdx.x;
  const int w   = tid >> 6;        // wave 0..7
  const int l   = tid & 63;        // lane
  const int wm  = w & 3;           // m-quarter
  const int wn  = w >> 2;          // block-row within pair (0=A,1=B)
  const int p   = blockIdx.x;
  const int rA  = ((p >> 1) << 2) + (p & 1);
  const int rB  = rA + 2;
  const int m0  = blockIdx.y * BM;

  const int startA = crow[rA], endA = crow[rA + 1];
  const int startB = crow[rB], endB = crow[rB + 1];

  const int lr = l & 15;           // MFMA m/n index within 16
  const int q  = l >> 4;           // quad 0..3 (k-chunk owner)

  // Preload both sorted col lists into lane registers (<=64 entries each).
  int cvA = (startA + l < endA) ? cols[startA + l] : 0;
  int cvB = (startB + l < endB) ? cols[startB + l] : 0;

  // ---- Precompute merged step table into lane-indexed registers. ----
  // Lane t holds step t: col (myc) and packed {sA, sB, hasA, hasB} (mypk).
  // sA/sB CLAMPED valid indices -> staging is branchless/uniform.
  int myc = 0, mypk = 0;
  int nt = 0;
  {
    int ia = startA, ib = startB;
    const int clA = (endA > startA) ? endA - 1 : 0;
    const int clB = (endB > startB) ? endB - 1 : 0;
    while ((ia < endA) || (ib < endB)) {
      const int ca = (ia < endA) ? __shfl(cvA, ia - startA) : 0x7fffffff;
      const int cb = (ib < endB) ? __shfl(cvB, ib - startB) : 0x7fffffff;
      const int c  = min(ca, cb);
      const int hA = (ca == c);
      const int hB = (cb == c);
      const int sA = hA ? ia : clA;
      const int sB = hB ? ib : clB;
      if (nt == l) { myc = c; mypk = sA | (sB << 12) | (hA << 24) | (hB << 25); }
      ia += hA; ib += hB; ++nt;
    }
  }

  f32x4 acc[4][4];
#pragma unroll
  for (int mi = 0; mi < 4; ++mi)
#pragma unroll
    for (int ni = 0; ni < 4; ++ni) {
      f32x4 z = {0.f, 0.f, 0.f, 0.f};
      acc[mi][ni] = z;
    }

  // Staging lane roles (512 threads, 64B rows):
  // thread tid -> LDS (row = tid>>2, slot = tid&3); must fetch global chunk
  // slot ^ g(row) with g(r) = (r>>1)&3  ->  (tid&3) ^ ((tid>>3)&3).
  // Row offsets of +128 (A second issue) and +16 (B n-rows) are multiples
  // of 16 -> g unchanged; one formula serves both A and B.
  const int swz8 = (((tid & 3) ^ ((tid >> 3) & 3)) << 3);      // elements
  const unsigned short* agbase =
      xb + (size_t)(m0 + (tid >> 2)) * IN_F + swz8;            // + c*64 + k0
  const int bgoff = (((tid & 255) >> 2) << 6) + swz8;          // elements
  const int bblk = tid >> 8;                                   // 0 or 1

  // Issue the 3 global_load_lds for half-step h into buffer buf.
  auto stage = [&](int h, int buf) {
    const int t  = h >> 1;
    const int k0 = (h & 1) << 5;                               // 0 or 32
    const int c  = __shfl(myc, t);
    const int pk = __shfl(mypk, t);
    const int sA = pk & 0xfff;
    const int sB = (pk >> 12) & 0xfff;
    char* const al = smem + buf * BUF_BYTES + tid * 16;
    char* const bl = smem + buf * BUF_BYTES + LDS_A_BYTES + tid * 16;
    const unsigned short* ag = agbase + (size_t)c * BS + k0;
    async_copy16(ag, al);                                      // rows 0..127
    async_copy16(ag + (size_t)128 * IN_F, al + 8192);          // rows 128..255
    const int sblk = bblk ? sB : sA;
    async_copy16(wb + ((size_t)sblk << 12) + bgoff + k0, bl);  // both W halves
  };

  // ---- 2-phase pipelined loop over half-steps (BK=32). ----
  // stage(h+1) issued first (latency hides under compute(h) + other WG),
  // compute reads buf[cur], ONE __syncthreads per half-step drains
  // vmcnt (stage h+1 complete) and fences buf[cur] for reuse.
  const int nh = nt << 1;
  if (nh > 0) stage(0, 0);
  __syncthreads();
  int cur = 0;
  for (int h = 0; h < nh; ++h) {
    if (h + 1 < nh) stage(h + 1, cur ^ 1);

    const int pk = __shfl(mypk, h >> 1);
    const char* const cbase = smem + cur * BUF_BYTES;
    if ((pk >> (24 + wn)) & 1) {                   // this wave's row has col c
      __builtin_amdgcn_s_setprio(1);
      // Read global chunk q of row r at LDS slot q ^ ((r>>1)&3); for all
      // rows used here r mod 16 == lr -> slot = q ^ ((lr>>1)&3).
      const int chunk = ((q ^ ((lr >> 1) & 3)) << 4);          // bytes
      s16x8 af[4], bf[4];
#pragma unroll
      for (int mi = 0; mi < 4; ++mi)   // A[m][k], swizzled chunk
        af[mi] = *(const s16x8*)(cbase +
                   ((wm << 6) + (mi << 4) + lr) * 64 + chunk);
#pragma unroll
      for (int ni = 0; ni < 4; ++ni)   // B^T[n][k], block wn
        bf[ni] = *(const s16x8*)(cbase + LDS_A_BYTES + (wn << 12) +
                   ((ni << 4) + lr) * 64 + chunk);
#pragma unroll
      for (int mi = 0; mi < 4; ++mi)
#pragma unroll
        for (int ni = 0; ni < 4; ++ni)
          acc[mi][ni] = __builtin_amdgcn_mfma_f32_16x16x32_bf16(
              af[mi], bf[ni], acc[mi][ni], 0, 0, 0);
      __builtin_amdgcn_s_setprio(0);
    }
    __syncthreads();
    cur ^= 1;
  }

  // Epilogue: C/D layout col=lr, row=q*4+reg. Add bias, store fp32.
  const int rW = wn ? rB : rA;
  const int colg = (rW << 6) + lr;
#pragma unroll
  for (int ni = 0; ni < 4; ++ni) {
    const float bv = bias[colg + (ni << 4)];
#pragma unroll
    for (int mi = 0; mi < 4; ++mi) {
      float* op = out +
          (size_t)(m0 + (wm << 6) + (mi << 4) + (q << 2)) * OUT_F +
          colg + (ni << 4);
#pragma unroll
      for (int e = 0; e < 4; ++e)
        op[(size_t)e * OUT_F] = acc[mi][ni][e] + bv;
    }
  }
}

// Safety net if ws_size < 84 MB: naive fp32, one thread per output element.
__global__ void fallback_kernel(const float* __restrict__ x,
                                const float* __restrict__ vals,
                                const float* __restrict__ bias,
                                const int* __restrict__ crow,
                                const int* __restrict__ cols,
                                float* __restrict__ out) {
  int idx = blockIdx.x * 256 + threadIdx.x;
  int m = idx >> 12;
  int n = idx & 4095;
  int r = n >> 6, nl = n & 63;
  float s = 0.f;
  int e = crow[r + 1];
  for (int i = crow[r]; i < e; ++i) {
    const float* xp = x + (size_t)m * IN_F + cols[i] * 64;
    const float* wp = vals + ((size_t)i << 12) + nl * 64;
    for (int k = 0; k < 64; ++k) s += xp[k] * wp[k];
  }
  out[idx] = s + bias[n];
}

extern "C" void kernel_launch(void* const* d_in, const int* in_sizes, int n_in,
                              void* d_out, int out_size, void* d_ws,
                              size_t ws_size, hipStream_t stream) {
  const float* x    = (const float*)d_in[0];
  const float* vals = (const float*)d_in[1];
  const float* bias = (const float*)d_in[2];
  const int*   crow = (const int*)d_in[3];
  const int*   cols = (const int*)d_in[4];
  float* out = (float*)d_out;

  const size_t x_elems = (size_t)BATCH * IN_F;       // 33.5M
  const size_t w_elems = (size_t)NNZB * BS * BS;     // 8.4M
  const size_t need = (x_elems + w_elems) * 2;       // bf16 bytes, ~84 MB

  if (ws_size >= need) {
    unsigned short* xb = (unsigned short*)d_ws;
    unsigned short* wbp = xb + x_elems;
    const int nx4 = (int)(x_elems / 4);
    const int ntot4 = (int)((x_elems + w_elems) / 4);
    cvt_kernel<<<(ntot4 + 255) / 256, 256, 0, stream>>>(
        (const float4*)x, (const float4*)vals,
        (ushort4*)xb, (ushort4*)wbp, nx4, ntot4);
    dim3 grid(NROW / 2, BATCH / BM);  // pair-fast: same x-slab hot in L2
    bsr_gemm_pair_kernel<<<grid, 512, 0, stream>>>(xb, wbp, bias, crow, cols,
                                                   out);
  } else {
    fallback_kernel<<<(BATCH * OUT_F) / 256, 256, 0, stream>>>(
        x, vals, bias, crow, cols, out);
  }
}